// Round 1
// baseline (318.618 us; speedup 1.0000x reference)
//
#include <hip/hip_runtime.h>
#include <hip/hip_bf16.h>
#include <math.h>

#define NTOK 65536
#define DMODEL 256
#define NEXP 8
#define CAP 65536

typedef __bf16 bf16_t;
typedef __bf16 bf16x8 __attribute__((ext_vector_type(8)));
typedef __bf16 bf16x4 __attribute__((ext_vector_type(4)));
typedef float f32x4 __attribute__((ext_vector_type(4)));

// async global->LDS, 16B per lane. LDS dest = wave-uniform base + lane*16.
__device__ inline void async16(const void* g, void* l) {
  __builtin_amdgcn_global_load_lds(
      (const __attribute__((address_space(1))) unsigned int*)g,
      (__attribute__((address_space(3))) unsigned int*)l, 16, 0, 0);
}

__global__ void zero_counts_kernel(int* counts) {
  if (threadIdx.x < NEXP) counts[threadIdx.x] = 0;
}

// Cast W1/W2 fp32 [e][k][n] -> bf16 transposed [e][n][k] via 32x32 LDS tile.
__global__ __launch_bounds__(256) void castT_kernel(
    const float* __restrict__ W1, const float* __restrict__ W2,
    bf16_t* __restrict__ w1t, bf16_t* __restrict__ w2t) {
  __shared__ float tile[32][33];
  const int m = blockIdx.z;
  const float* src = (m < 8) ? (W1 + (size_t)m * 65536) : (W2 + (size_t)(m - 8) * 65536);
  bf16_t* dst = (m < 8) ? (w1t + (size_t)m * 65536) : (w2t + (size_t)(m - 8) * 65536);
  const int x0 = blockIdx.x * 32, y0 = blockIdx.y * 32;
  const int tx = threadIdx.x, ty = threadIdx.y;
#pragma unroll
  for (int i = 0; i < 4; ++i)
    tile[ty + i * 8][tx] = src[(size_t)(y0 + ty + i * 8) * 256 + x0 + tx];
  __syncthreads();
#pragma unroll
  for (int i = 0; i < 4; ++i)
    dst[(size_t)(x0 + ty + i * 8) * 256 + y0 + tx] = (bf16_t)tile[tx][ty + i * 8];
}

// Gate: fp64 logits (argmax must match numpy), softmax top-1 value,
// x -> bf16 cast, ballot-aggregated bucket scatter. 256 tokens/block.
__global__ __launch_bounds__(256) void gate_kernel(
    const float* __restrict__ x, const float* __restrict__ wg,
    bf16_t* __restrict__ xb, float* __restrict__ gateval,
    int* __restrict__ counts, int* __restrict__ idxbuf) {
  __shared__ __align__(16) float Lx[256 * 36];  // pad 32->36 (16B-aligned rows, no conflicts)
  __shared__ __align__(16) float Lwg[256];
  const int th = threadIdx.x;
  const int T0 = blockIdx.x * 256;
  double acc[8] = {0, 0, 0, 0, 0, 0, 0, 0};
  for (int c = 0; c < 8; ++c) {  // 8 chunks of 32 dims
#pragma unroll
    for (int i = 0; i < 8; ++i) {
      int f = th + i * 256;          // float4 id within [256 tok][8 quads]
      int tok = f >> 3, p = f & 7;
      float4 v = *(const float4*)(x + (size_t)(T0 + tok) * 256 + c * 32 + p * 4);
      float* lp = &Lx[tok * 36 + p * 4];
      lp[0] = v.x; lp[1] = v.y; lp[2] = v.z; lp[3] = v.w;
      bf16x4 bv;
      bv[0] = (bf16_t)v.x; bv[1] = (bf16_t)v.y; bv[2] = (bf16_t)v.z; bv[3] = (bf16_t)v.w;
      *(bf16x4*)(xb + (size_t)(T0 + tok) * 256 + c * 32 + p * 4) = bv;
    }
    Lwg[th] = wg[(th >> 5) * 256 + c * 32 + (th & 31)];
    __syncthreads();
    const float4* Lx4 = (const float4*)&Lx[th * 36];
    const float4* Lwg4 = (const float4*)Lwg;
#pragma unroll
    for (int kq = 0; kq < 8; ++kq) {
      float4 xq = Lx4[kq];
#pragma unroll
      for (int e = 0; e < 8; ++e) {
        float4 wq = Lwg4[e * 8 + kq];
        acc[e] += (double)xq.x * wq.x + (double)xq.y * wq.y +
                  (double)xq.z * wq.z + (double)xq.w * wq.w;
      }
    }
    __syncthreads();
  }
  // argmax (first max, matches jnp.argmax) + top-1 softmax value
  double m = acc[0]; int bi = 0;
#pragma unroll
  for (int e = 1; e < 8; ++e) if (acc[e] > m) { m = acc[e]; bi = e; }
  double denom = 0.0;
#pragma unroll
  for (int e = 0; e < 8; ++e) denom += exp(acc[e] - m);
  gateval[T0 + th] = (float)(1.0 / denom);

  const int lane = th & 63;
#pragma unroll
  for (int e = 0; e < NEXP; ++e) {
    unsigned long long mask = __ballot(bi == e);
    if (mask) {
      int leader = __ffsll(mask) - 1;
      int base = 0;
      if (lane == leader) base = atomicAdd(&counts[e], __popcll(mask));
      base = __shfl(base, leader, 64);
      if (bi == e) {
        int pos = base + (int)__popcll(mask & ((1ull << lane) - 1ull));
        idxbuf[e * CAP + pos] = T0 + th;
      }
    }
  }
}

__global__ void scan_kernel(const int* __restrict__ counts, int* __restrict__ bases) {
  if (threadIdx.x == 0) {
    int s = 0;
    for (int e = 0; e < NEXP; ++e) { bases[e] = s; s += counts[e]; }
  }
}

// GEMM1: h[slot][n] = relu(x[idx[slot]] @ W1[e] + b1[e]), bf16 out.
// Tile 128(M) x 128(N), BK=64, 4 waves each 64x64 (4x4 frags of 16x16x32).
__global__ __launch_bounds__(256) void gemm1_kernel(
    const bf16_t* __restrict__ xb, const bf16_t* __restrict__ w1t,
    const float* __restrict__ b1, const int* __restrict__ counts,
    const int* __restrict__ bases, const int* __restrict__ idxbuf,
    bf16_t* __restrict__ h) {
  const int e = blockIdx.z;
  const int cnt = counts[e];
  const int tm = blockIdx.x;
  if (tm * 128 >= cnt) return;
  const int nt = blockIdx.y;
  const int bse = bases[e];
  __shared__ __align__(16) bf16_t As[128 * 64];
  __shared__ __align__(16) bf16_t Bs[128 * 64];
  __shared__ int sidx[128];
  const int th = threadIdx.x;
  const int ln = th & 63, wv = th >> 6;
  if (th < 128) {
    int r = tm * 128 + th;
    sidx[th] = idxbuf[e * CAP + (r < cnt ? r : cnt - 1)];
  }
  __syncthreads();
  f32x4 acc[4][4] = {};
  const bf16_t* w1e = w1t + (size_t)e * 65536;
  const int wm = (wv & 1) * 64, wn = (wv >> 1) * 64;
  const int lr = ln & 15, lq = ln >> 4;
  for (int kk = 0; kk < 256; kk += 64) {
#pragma unroll
    for (int i = 0; i < 4; ++i) {
      int c = i * 256 + th;               // 16B chunk id, A: [128 r][8 j]
      int r = c >> 3, j = c & 7;
      async16(xb + (size_t)sidx[r] * 256 + kk + j * 8, &As[(i * 256 + wv * 64) * 8]);
    }
#pragma unroll
    for (int i = 0; i < 4; ++i) {
      int c = i * 256 + th;               // B: [128 n][8 j] from W1t[e][n][k]
      int n = c >> 3, j = c & 7;
      async16(w1e + (size_t)(nt * 128 + n) * 256 + kk + j * 8, &Bs[(i * 256 + wv * 64) * 8]);
    }
    __syncthreads();
#pragma unroll
    for (int kb = 0; kb < 2; ++kb) {
      bf16x8 af[4], bfr[4];
#pragma unroll
      for (int mi = 0; mi < 4; ++mi)
        af[mi] = *(const bf16x8*)&As[(wm + mi * 16 + lr) * 64 + kb * 32 + lq * 8];
#pragma unroll
      for (int ni = 0; ni < 4; ++ni)
        bfr[ni] = *(const bf16x8*)&Bs[(wn + ni * 16 + lr) * 64 + kb * 32 + lq * 8];
#pragma unroll
      for (int mi = 0; mi < 4; ++mi)
#pragma unroll
        for (int ni = 0; ni < 4; ++ni)
          acc[mi][ni] = __builtin_amdgcn_mfma_f32_16x16x32_bf16(af[mi], bfr[ni], acc[mi][ni], 0, 0, 0);
    }
    __syncthreads();
  }
#pragma unroll
  for (int ni = 0; ni < 4; ++ni) {
    int n = nt * 128 + wn + ni * 16 + lr;
    float bias = b1[e * 256 + n];
#pragma unroll
    for (int mi = 0; mi < 4; ++mi) {
#pragma unroll
      for (int r = 0; r < 4; ++r) {
        int rowb = wm + mi * 16 + lq * 4 + r;   // C layout: col=lane&15, row=quad*4+reg
        int row = tm * 128 + rowb;
        if (row < cnt) {
          float v = acc[mi][ni][r] + bias;
          v = v > 0.f ? v : 0.f;
          h[(size_t)(bse + row) * 256 + n] = (bf16_t)v;
        }
      }
    }
  }
}

// GEMM2: out[tok][n] = (h[slot] @ W2[e] + b2[e]) * gate, scattered fp32 store.
__global__ __launch_bounds__(256) void gemm2_kernel(
    const bf16_t* __restrict__ h, const bf16_t* __restrict__ w2t,
    const float* __restrict__ b2, const float* __restrict__ gateval,
    const int* __restrict__ counts, const int* __restrict__ bases,
    const int* __restrict__ idxbuf, float* __restrict__ out) {
  const int e = blockIdx.z;
  const int cnt = counts[e];
  const int tm = blockIdx.x;
  if (tm * 128 >= cnt) return;
  const int nt = blockIdx.y;
  const int bse = bases[e];
  __shared__ __align__(16) bf16_t As[128 * 64];
  __shared__ __align__(16) bf16_t Bs[128 * 64];
  __shared__ int sidx[128];
  __shared__ float sgv[128];
  const int th = threadIdx.x;
  const int ln = th & 63, wv = th >> 6;
  if (th < 128) {
    int r = tm * 128 + th;
    int t = idxbuf[e * CAP + (r < cnt ? r : cnt - 1)];
    sidx[th] = t;
    sgv[th] = gateval[t];
  }
  __syncthreads();
  f32x4 acc[4][4] = {};
  const bf16_t* w2e = w2t + (size_t)e * 65536;
  const int wm = (wv & 1) * 64, wn = (wv >> 1) * 64;
  const int lr = ln & 15, lq = ln >> 4;
  for (int kk = 0; kk < 256; kk += 64) {
#pragma unroll
    for (int i = 0; i < 4; ++i) {
      int c = i * 256 + th;
      int r = c >> 3, j = c & 7;
      int rg = tm * 128 + r; rg = rg < cnt ? rg : cnt - 1;
      async16(h + (size_t)(bse + rg) * 256 + kk + j * 8, &As[(i * 256 + wv * 64) * 8]);
    }
#pragma unroll
    for (int i = 0; i < 4; ++i) {
      int c = i * 256 + th;
      int n = c >> 3, j = c & 7;
      async16(w2e + (size_t)(nt * 128 + n) * 256 + kk + j * 8, &Bs[(i * 256 + wv * 64) * 8]);
    }
    __syncthreads();
#pragma unroll
    for (int kb = 0; kb < 2; ++kb) {
      bf16x8 af[4], bfr[4];
#pragma unroll
      for (int mi = 0; mi < 4; ++mi)
        af[mi] = *(const bf16x8*)&As[(wm + mi * 16 + lr) * 64 + kb * 32 + lq * 8];
#pragma unroll
      for (int ni = 0; ni < 4; ++ni)
        bfr[ni] = *(const bf16x8*)&Bs[(wn + ni * 16 + lr) * 64 + kb * 32 + lq * 8];
#pragma unroll
      for (int mi = 0; mi < 4; ++mi)
#pragma unroll
        for (int ni = 0; ni < 4; ++ni)
          acc[mi][ni] = __builtin_amdgcn_mfma_f32_16x16x32_bf16(af[mi], bfr[ni], acc[mi][ni], 0, 0, 0);
    }
    __syncthreads();
  }
#pragma unroll
  for (int ni = 0; ni < 4; ++ni) {
    int n = nt * 128 + wn + ni * 16 + lr;
    float bias = b2[e * 256 + n];
#pragma unroll
    for (int mi = 0; mi < 4; ++mi) {
#pragma unroll
      for (int r = 0; r < 4; ++r) {
        int rowb = wm + mi * 16 + lq * 4 + r;
        int row = tm * 128 + rowb;
        if (row < cnt) {
          int tok = sidx[rowb];
          out[(size_t)tok * 256 + n] = (acc[mi][ni][r] + bias) * sgv[rowb];
        }
      }
    }
  }
}

extern "C" void kernel_launch(void* const* d_in, const int* in_sizes, int n_in,
                              void* d_out, int out_size, void* d_ws, size_t ws_size,
                              hipStream_t stream) {
  (void)in_sizes; (void)n_in; (void)out_size; (void)ws_size;
  const float* x  = (const float*)d_in[0];
  const float* wg = (const float*)d_in[1];
  const float* W1 = (const float*)d_in[2];
  const float* b1 = (const float*)d_in[3];
  const float* W2 = (const float*)d_in[4];
  const float* b2 = (const float*)d_in[5];
  float* out = (float*)d_out;

  char* ws = (char*)d_ws;
  size_t off = 0;
  auto alloc = [&](size_t bytes) {
    void* p = ws + off;
    off += (bytes + 255) & ~(size_t)255;
    return p;
  };
  bf16_t* xb     = (bf16_t*)alloc((size_t)NTOK * DMODEL * 2);   // 32 MB
  bf16_t* hbuf   = (bf16_t*)alloc((size_t)NTOK * DMODEL * 2);   // 32 MB
  bf16_t* w1t    = (bf16_t*)alloc((size_t)NEXP * 256 * 256 * 2);
  bf16_t* w2t    = (bf16_t*)alloc((size_t)NEXP * 256 * 256 * 2);
  int*    idxbuf = (int*)alloc((size_t)NEXP * CAP * 4);         // 2 MB
  float*  gv     = (float*)alloc((size_t)NTOK * 4);
  int*    counts = (int*)alloc(64);
  int*    bases  = (int*)alloc(64);

  hipLaunchKernelGGL(zero_counts_kernel, dim3(1), dim3(64), 0, stream, counts);
  hipLaunchKernelGGL(castT_kernel, dim3(8, 8, 16), dim3(32, 8), 0, stream, W1, W2, w1t, w2t);
  hipLaunchKernelGGL(gate_kernel, dim3(NTOK / 256), dim3(256), 0, stream,
                     x, wg, xb, gv, counts, idxbuf);
  hipLaunchKernelGGL(scan_kernel, dim3(1), dim3(64), 0, stream, counts, bases);
  hipLaunchKernelGGL(gemm1_kernel, dim3(512, 2, NEXP), dim3(256), 0, stream,
                     xb, w1t, b1, counts, bases, idxbuf, hbuf);
  hipLaunchKernelGGL(gemm2_kernel, dim3(512, 2, NEXP), dim3(256), 0, stream,
                     hbuf, w2t, b2, gv, counts, bases, idxbuf, out);
}

// Round 2
// 299.999 us; speedup vs baseline: 1.0621x; 1.0621x over previous
//
#include <hip/hip_runtime.h>
#include <hip/hip_bf16.h>
#include <math.h>

#define NTOK 65536
#define DMODEL 256
#define NEXP 8
#define CAP 65536

typedef __bf16 bf16_t;
typedef __bf16 bf16x8 __attribute__((ext_vector_type(8)));
typedef __bf16 bf16x4 __attribute__((ext_vector_type(4)));
typedef float f32x4 __attribute__((ext_vector_type(4)));

// async global->LDS, 16B per lane. LDS dest = wave-uniform base + lane*16.
__device__ inline void async16(const void* g, void* l) {
  __builtin_amdgcn_global_load_lds(
      (const __attribute__((address_space(1))) unsigned int*)g,
      (__attribute__((address_space(3))) unsigned int*)l, 16, 0, 0);
}

// Prep: zero expert counters + cast wg fp32 -> fp64 (enables s_load_dwordx2
// broadcast operands in the gate's fp64 FMA loop, no per-element cvt).
__global__ void prep_kernel(const float* __restrict__ wg, double* __restrict__ wgd,
                            int* __restrict__ counts) {
  int t = blockIdx.x * 256 + threadIdx.x;
  if (t < NEXP * DMODEL) wgd[t] = (double)wg[t];
  if (blockIdx.x == 0 && threadIdx.x < NEXP) counts[threadIdx.x] = 0;
}

// Cast W1/W2 fp32 [e][k][n] -> bf16 transposed [e][n][k] via 32x32 LDS tile.
__global__ __launch_bounds__(256) void castT_kernel(
    const float* __restrict__ W1, const float* __restrict__ W2,
    bf16_t* __restrict__ w1t, bf16_t* __restrict__ w2t) {
  __shared__ float tile[32][33];
  const int m = blockIdx.z;
  const float* src = (m < 8) ? (W1 + (size_t)m * 65536) : (W2 + (size_t)(m - 8) * 65536);
  bf16_t* dst = (m < 8) ? (w1t + (size_t)m * 65536) : (w2t + (size_t)(m - 8) * 65536);
  const int x0 = blockIdx.x * 32, y0 = blockIdx.y * 32;
  const int tx = threadIdx.x, ty = threadIdx.y;
#pragma unroll
  for (int i = 0; i < 4; ++i)
    tile[ty + i * 8][tx] = src[(size_t)(y0 + ty + i * 8) * 256 + x0 + tx];
  __syncthreads();
#pragma unroll
  for (int i = 0; i < 4; ++i)
    dst[(size_t)(x0 + ty + i * 8) * 256 + y0 + tx] = (bf16_t)tile[tx][ty + i * 8];
}

// Gate v2: 512 blocks x 256 thr. Each thread owns HALF a token row (128 dims)
// fully in registers; waves 0/1 (and 2/3) pair up on 64 tokens, halves q=0/1.
// q is wave-uniform (readfirstlane) so wgd loads become scalar broadcasts.
// One LDS exchange + one barrier for the cross-wave reduction. fp64 logits
// (argmax must track numpy fp32 softmax argmax; validated R1).
__global__ __launch_bounds__(256) void gate_kernel(
    const float* __restrict__ x, const double* __restrict__ wgd,
    bf16_t* __restrict__ xb, float* __restrict__ gateval,
    int* __restrict__ counts, int* __restrict__ idxbuf) {
  __shared__ double partial[128][9];  // [token slot][8 accs + pad]
  const int th = threadIdx.x;
  const int w = th >> 6, lane = th & 63;
  const int tgrp = w >> 1;
  const int q = __builtin_amdgcn_readfirstlane(w & 1);  // half id, wave-uniform
  const int tslot = tgrp * 64 + lane;
  const int tok = blockIdx.x * 128 + tslot;
  const float* xrow = x + (size_t)tok * 256 + q * 128;
  bf16_t* xbrow = xb + (size_t)tok * 256 + q * 128;
  const double* wgq = wgd + q * 128;
  double acc[8] = {0, 0, 0, 0, 0, 0, 0, 0};
#pragma unroll
  for (int c = 0; c < 4; ++c) {  // 4 chunks of 32 dims
    float4 xv[8];
#pragma unroll
    for (int j = 0; j < 8; ++j)
      xv[j] = *(const float4*)(xrow + c * 32 + j * 4);
#pragma unroll
    for (int j = 0; j < 8; ++j) {
      bf16x4 bv;
      bv[0] = (bf16_t)xv[j].x; bv[1] = (bf16_t)xv[j].y;
      bv[2] = (bf16_t)xv[j].z; bv[3] = (bf16_t)xv[j].w;
      *(bf16x4*)(xbrow + c * 32 + j * 4) = bv;
    }
    double xd[32];
#pragma unroll
    for (int j = 0; j < 8; ++j) {
      xd[j * 4 + 0] = (double)xv[j].x;
      xd[j * 4 + 1] = (double)xv[j].y;
      xd[j * 4 + 2] = (double)xv[j].z;
      xd[j * 4 + 3] = (double)xv[j].w;
    }
#pragma unroll
    for (int e = 0; e < 8; ++e) {
      const double* wp = wgq + e * 256 + c * 32;  // uniform -> scalar loads
#pragma unroll
      for (int d = 0; d < 32; ++d)
        acc[e] += xd[d] * wp[d];
    }
  }
  if (q == 1) {
#pragma unroll
    for (int e = 0; e < 8; ++e) partial[tslot][e] = acc[e];
  }
  __syncthreads();
  if (q == 0) {
#pragma unroll
    for (int e = 0; e < 8; ++e) acc[e] += partial[tslot][e];
    double m = acc[0]; int bi = 0;
#pragma unroll
    for (int e = 1; e < 8; ++e) if (acc[e] > m) { m = acc[e]; bi = e; }
    double denom = 0.0;
#pragma unroll
    for (int e = 0; e < 8; ++e) denom += exp(acc[e] - m);
    gateval[tok] = (float)(1.0 / denom);
    // ballot-aggregated bucket scatter: 8 atomics per wave max
#pragma unroll
    for (int e = 0; e < NEXP; ++e) {
      unsigned long long mask = __ballot(bi == e);
      if (mask) {
        int leader = __ffsll(mask) - 1;
        int base = 0;
        if (lane == leader) base = atomicAdd(&counts[e], __popcll(mask));
        base = __shfl(base, leader, 64);
        if (bi == e) {
          int pos = base + (int)__popcll(mask & ((1ull << lane) - 1ull));
          idxbuf[e * CAP + pos] = tok;
        }
      }
    }
  }
}

__global__ void scan_kernel(const int* __restrict__ counts, int* __restrict__ bases) {
  if (threadIdx.x == 0) {
    int s = 0;
    for (int e = 0; e < NEXP; ++e) { bases[e] = s; s += counts[e]; }
  }
}

// GEMM1: h[slot][n] = relu(x[idx[slot]] @ W1[e] + b1[e]), bf16 out.
// Tile 128(M) x 128(N), BK=64, 4 waves each 64x64 (4x4 frags of 16x16x32).
__global__ __launch_bounds__(256) void gemm1_kernel(
    const bf16_t* __restrict__ xb, const bf16_t* __restrict__ w1t,
    const float* __restrict__ b1, const int* __restrict__ counts,
    const int* __restrict__ bases, const int* __restrict__ idxbuf,
    bf16_t* __restrict__ h) {
  const int e = blockIdx.z;
  const int cnt = counts[e];
  const int tm = blockIdx.x;
  if (tm * 128 >= cnt) return;
  const int nt = blockIdx.y;
  const int bse = bases[e];
  __shared__ __align__(16) bf16_t As[128 * 64];
  __shared__ __align__(16) bf16_t Bs[128 * 64];
  __shared__ int sidx[128];
  const int th = threadIdx.x;
  const int ln = th & 63, wv = th >> 6;
  if (th < 128) {
    int r = tm * 128 + th;
    sidx[th] = idxbuf[e * CAP + (r < cnt ? r : cnt - 1)];
  }
  __syncthreads();
  f32x4 acc[4][4] = {};
  const bf16_t* w1e = w1t + (size_t)e * 65536;
  const int wm = (wv & 1) * 64, wn = (wv >> 1) * 64;
  const int lr = ln & 15, lq = ln >> 4;
  for (int kk = 0; kk < 256; kk += 64) {
#pragma unroll
    for (int i = 0; i < 4; ++i) {
      int c = i * 256 + th;               // 16B chunk id, A: [128 r][8 j]
      int r = c >> 3, j = c & 7;
      async16(xb + (size_t)sidx[r] * 256 + kk + j * 8, &As[(i * 256 + wv * 64) * 8]);
    }
#pragma unroll
    for (int i = 0; i < 4; ++i) {
      int c = i * 256 + th;               // B: [128 n][8 j] from W1t[e][n][k]
      int n = c >> 3, j = c & 7;
      async16(w1e + (size_t)(nt * 128 + n) * 256 + kk + j * 8, &Bs[(i * 256 + wv * 64) * 8]);
    }
    __syncthreads();
#pragma unroll
    for (int kb = 0; kb < 2; ++kb) {
      bf16x8 af[4], bfr[4];
#pragma unroll
      for (int mi = 0; mi < 4; ++mi)
        af[mi] = *(const bf16x8*)&As[(wm + mi * 16 + lr) * 64 + kb * 32 + lq * 8];
#pragma unroll
      for (int ni = 0; ni < 4; ++ni)
        bfr[ni] = *(const bf16x8*)&Bs[(wn + ni * 16 + lr) * 64 + kb * 32 + lq * 8];
#pragma unroll
      for (int mi = 0; mi < 4; ++mi)
#pragma unroll
        for (int ni = 0; ni < 4; ++ni)
          acc[mi][ni] = __builtin_amdgcn_mfma_f32_16x16x32_bf16(af[mi], bfr[ni], acc[mi][ni], 0, 0, 0);
    }
    __syncthreads();
  }
#pragma unroll
  for (int ni = 0; ni < 4; ++ni) {
    int n = nt * 128 + wn + ni * 16 + lr;
    float bias = b1[e * 256 + n];
#pragma unroll
    for (int mi = 0; mi < 4; ++mi) {
#pragma unroll
      for (int r = 0; r < 4; ++r) {
        int rowb = wm + mi * 16 + lq * 4 + r;   // C layout: col=lane&15, row=quad*4+reg
        int row = tm * 128 + rowb;
        if (row < cnt) {
          float v = acc[mi][ni][r] + bias;
          v = v > 0.f ? v : 0.f;
          h[(size_t)(bse + row) * 256 + n] = (bf16_t)v;
        }
      }
    }
  }
}

// GEMM2: out[tok][n] = (h[slot] @ W2[e] + b2[e]) * gate, scattered fp32 store.
__global__ __launch_bounds__(256) void gemm2_kernel(
    const bf16_t* __restrict__ h, const bf16_t* __restrict__ w2t,
    const float* __restrict__ b2, const float* __restrict__ gateval,
    const int* __restrict__ counts, const int* __restrict__ bases,
    const int* __restrict__ idxbuf, float* __restrict__ out) {
  const int e = blockIdx.z;
  const int cnt = counts[e];
  const int tm = blockIdx.x;
  if (tm * 128 >= cnt) return;
  const int nt = blockIdx.y;
  const int bse = bases[e];
  __shared__ __align__(16) bf16_t As[128 * 64];
  __shared__ __align__(16) bf16_t Bs[128 * 64];
  __shared__ int sidx[128];
  __shared__ float sgv[128];
  const int th = threadIdx.x;
  const int ln = th & 63, wv = th >> 6;
  if (th < 128) {
    int r = tm * 128 + th;
    int t = idxbuf[e * CAP + (r < cnt ? r : cnt - 1)];
    sidx[th] = t;
    sgv[th] = gateval[t];
  }
  __syncthreads();
  f32x4 acc[4][4] = {};
  const bf16_t* w2e = w2t + (size_t)e * 65536;
  const int wm = (wv & 1) * 64, wn = (wv >> 1) * 64;
  const int lr = ln & 15, lq = ln >> 4;
  for (int kk = 0; kk < 256; kk += 64) {
#pragma unroll
    for (int i = 0; i < 4; ++i) {
      int c = i * 256 + th;
      int r = c >> 3, j = c & 7;
      int rg = tm * 128 + r; rg = rg < cnt ? rg : cnt - 1;
      async16(h + (size_t)(bse + rg) * 256 + kk + j * 8, &As[(i * 256 + wv * 64) * 8]);
    }
#pragma unroll
    for (int i = 0; i < 4; ++i) {
      int c = i * 256 + th;
      int n = c >> 3, j = c & 7;
      async16(w2e + (size_t)(nt * 128 + n) * 256 + kk + j * 8, &Bs[(i * 256 + wv * 64) * 8]);
    }
    __syncthreads();
#pragma unroll
    for (int kb = 0; kb < 2; ++kb) {
      bf16x8 af[4], bfr[4];
#pragma unroll
      for (int mi = 0; mi < 4; ++mi)
        af[mi] = *(const bf16x8*)&As[(wm + mi * 16 + lr) * 64 + kb * 32 + lq * 8];
#pragma unroll
      for (int ni = 0; ni < 4; ++ni)
        bfr[ni] = *(const bf16x8*)&Bs[(wn + ni * 16 + lr) * 64 + kb * 32 + lq * 8];
#pragma unroll
      for (int mi = 0; mi < 4; ++mi)
#pragma unroll
        for (int ni = 0; ni < 4; ++ni)
          acc[mi][ni] = __builtin_amdgcn_mfma_f32_16x16x32_bf16(af[mi], bfr[ni], acc[mi][ni], 0, 0, 0);
    }
    __syncthreads();
  }
#pragma unroll
  for (int ni = 0; ni < 4; ++ni) {
    int n = nt * 128 + wn + ni * 16 + lr;
    float bias = b2[e * 256 + n];
#pragma unroll
    for (int mi = 0; mi < 4; ++mi) {
#pragma unroll
      for (int r = 0; r < 4; ++r) {
        int rowb = wm + mi * 16 + lq * 4 + r;
        int row = tm * 128 + rowb;
        if (row < cnt) {
          int tok = sidx[rowb];
          out[(size_t)tok * 256 + n] = (acc[mi][ni][r] + bias) * sgv[rowb];
        }
      }
    }
  }
}

extern "C" void kernel_launch(void* const* d_in, const int* in_sizes, int n_in,
                              void* d_out, int out_size, void* d_ws, size_t ws_size,
                              hipStream_t stream) {
  (void)in_sizes; (void)n_in; (void)out_size; (void)ws_size;
  const float* x  = (const float*)d_in[0];
  const float* wg = (const float*)d_in[1];
  const float* W1 = (const float*)d_in[2];
  const float* b1 = (const float*)d_in[3];
  const float* W2 = (const float*)d_in[4];
  const float* b2 = (const float*)d_in[5];
  float* out = (float*)d_out;

  char* ws = (char*)d_ws;
  size_t off = 0;
  auto alloc = [&](size_t bytes) {
    void* p = ws + off;
    off += (bytes + 255) & ~(size_t)255;
    return p;
  };
  bf16_t* xb     = (bf16_t*)alloc((size_t)NTOK * DMODEL * 2);   // 32 MB
  bf16_t* hbuf   = (bf16_t*)alloc((size_t)NTOK * DMODEL * 2);   // 32 MB
  bf16_t* w1t    = (bf16_t*)alloc((size_t)NEXP * 256 * 256 * 2);
  bf16_t* w2t    = (bf16_t*)alloc((size_t)NEXP * 256 * 256 * 2);
  int*    idxbuf = (int*)alloc((size_t)NEXP * CAP * 4);         // 2 MB
  float*  gv     = (float*)alloc((size_t)NTOK * 4);
  double* wgd    = (double*)alloc((size_t)NEXP * DMODEL * 8);
  int*    counts = (int*)alloc(64);
  int*    bases  = (int*)alloc(64);

  hipLaunchKernelGGL(prep_kernel, dim3(8), dim3(256), 0, stream, wg, wgd, counts);
  hipLaunchKernelGGL(castT_kernel, dim3(8, 8, 16), dim3(32, 8), 0, stream, W1, W2, w1t, w2t);
  hipLaunchKernelGGL(gate_kernel, dim3(NTOK / 128), dim3(256), 0, stream,
                     x, wgd, xb, gv, counts, idxbuf);
  hipLaunchKernelGGL(scan_kernel, dim3(1), dim3(64), 0, stream, counts, bases);
  hipLaunchKernelGGL(gemm1_kernel, dim3(512, 2, NEXP), dim3(256), 0, stream,
                     xb, w1t, b1, counts, bases, idxbuf, hbuf);
  hipLaunchKernelGGL(gemm2_kernel, dim3(512, 2, NEXP), dim3(256), 0, stream,
                     hbuf, w2t, b2, gv, counts, bases, idxbuf, out);
}

// Round 3
// 286.700 us; speedup vs baseline: 1.1113x; 1.0464x over previous
//
#include <hip/hip_runtime.h>
#include <hip/hip_bf16.h>
#include <math.h>

#define NTOK 65536
#define DMODEL 256
#define NEXP 8
#define CAP 65536

typedef __bf16 bf16_t;
typedef __bf16 bf16x8 __attribute__((ext_vector_type(8)));
typedef __bf16 bf16x4 __attribute__((ext_vector_type(4)));
typedef float f32x4 __attribute__((ext_vector_type(4)));

// async global->LDS, 16B per lane. LDS dest = wave-uniform base + lane*16.
__device__ inline void async16(const void* g, void* l) {
  __builtin_amdgcn_global_load_lds(
      (const __attribute__((address_space(1))) unsigned int*)g,
      (__attribute__((address_space(3))) unsigned int*)l, 16, 0, 0);
}

// Prep: zero counters + transpose gate weights fp32 [E][D] -> [D][E]
// (gives 256B-contiguous [8 dims][8 experts] slices -> s_load_dwordx16).
__global__ void prep_kernel(const float* __restrict__ wg, float* __restrict__ wgT,
                            int* __restrict__ counts) {
  int t = blockIdx.x * 256 + threadIdx.x;
  if (t < NEXP * DMODEL) wgT[t] = wg[(t & 7) * 256 + (t >> 3)];
  if (blockIdx.x == 0 && threadIdx.x < NEXP) counts[threadIdx.x] = 0;
}

// Cast W1/W2 fp32 [e][k][n] -> bf16 transposed [e][n][k] via 32x32 LDS tile.
__global__ __launch_bounds__(256) void castT_kernel(
    const float* __restrict__ W1, const float* __restrict__ W2,
    bf16_t* __restrict__ w1t, bf16_t* __restrict__ w2t) {
  __shared__ float tile[32][33];
  const int m = blockIdx.z;
  const float* src = (m < 8) ? (W1 + (size_t)m * 65536) : (W2 + (size_t)(m - 8) * 65536);
  bf16_t* dst = (m < 8) ? (w1t + (size_t)m * 65536) : (w2t + (size_t)(m - 8) * 65536);
  const int x0 = blockIdx.x * 32, y0 = blockIdx.y * 32;
  const int tx = threadIdx.x, ty = threadIdx.y;
#pragma unroll
  for (int i = 0; i < 4; ++i)
    tile[ty + i * 8][tx] = src[(size_t)(y0 + ty + i * 8) * 256 + x0 + tx];
  __syncthreads();
#pragma unroll
  for (int i = 0; i < 4; ++i)
    dst[(size_t)(x0 + ty + i * 8) * 256 + y0 + tx] = (bf16_t)tile[tx][ty + i * 8];
}

// Gate v4: 1024 blocks x 512 thr = 32 waves/CU (hardware max occupancy).
// Thread owns 32 dims of one token; wave id == dim-segment (uniform -> all
// gate-weight reads are s_load_dwordx16 scalar broadcasts, off the vector
// dependency chain). Dot product: 8-dim fp32 fma chains accumulated into
// fp64 group sums (err ~3e-7 << numpy fp32's own ~5e-6; argmax-safe).
// One LDS exchange combines the 8 segments; wave 0 does softmax + scatter.
__global__ __launch_bounds__(512, 4) void gate_kernel(
    const float* __restrict__ x, const float* __restrict__ wgT,
    bf16_t* __restrict__ xb, float* __restrict__ gateval,
    int* __restrict__ counts, int* __restrict__ idxbuf) {
  __shared__ double part[7][64][9];  // +1 pad: 18-word stride, 2-way (free)
  const int lane = threadIdx.x & 63;
  const int seg = __builtin_amdgcn_readfirstlane(threadIdx.x >> 6);  // 0..7
  const int tok = blockIdx.x * 64 + lane;
  const float* xrow = x + (size_t)tok * 256 + seg * 32;
  bf16_t* xbrow = xb + (size_t)tok * 256 + seg * 32;
  const float* wp = wgT + seg * 32 * 8;  // [32 dims][8 experts], uniform
  double acc[8] = {0, 0, 0, 0, 0, 0, 0, 0};
#pragma unroll
  for (int g = 0; g < 4; ++g) {  // 8 dims per group
    float4 a = *(const float4*)(xrow + g * 8);
    float4 b = *(const float4*)(xrow + g * 8 + 4);
    float xv[8] = {a.x, a.y, a.z, a.w, b.x, b.y, b.z, b.w};
    bf16x8 bv;
#pragma unroll
    for (int j = 0; j < 8; ++j) bv[j] = (bf16_t)xv[j];
    *(bf16x8*)(xbrow + g * 8) = bv;
#pragma unroll
    for (int e = 0; e < 8; ++e) {
      float s = 0.f;
#pragma unroll
      for (int j = 0; j < 8; ++j)
        s = fmaf(xv[j], wp[(g * 8 + j) * 8 + e], s);
      acc[e] += (double)s;
    }
  }
  if (seg > 0) {
#pragma unroll
    for (int e = 0; e < 8; ++e) part[seg - 1][lane][e] = acc[e];
  }
  __syncthreads();
  if (seg == 0) {
#pragma unroll
    for (int s2 = 0; s2 < 7; ++s2)
#pragma unroll
      for (int e = 0; e < 8; ++e) acc[e] += part[s2][lane][e];
    double m = acc[0]; int bi = 0;
#pragma unroll
    for (int e = 1; e < 8; ++e) if (acc[e] > m) { m = acc[e]; bi = e; }
    float denom = 0.f;
#pragma unroll
    for (int e = 0; e < 8; ++e) denom += __expf((float)(acc[e] - m));
    gateval[tok] = 1.0f / denom;
    // ballot-aggregated bucket scatter: <=8 atomics per wave
#pragma unroll
    for (int e = 0; e < NEXP; ++e) {
      unsigned long long mask = __ballot(bi == e);
      if (mask) {
        int leader = __ffsll(mask) - 1;
        int base = 0;
        if (lane == leader) base = atomicAdd(&counts[e], __popcll(mask));
        base = __shfl(base, leader, 64);
        if (bi == e) {
          int pos = base + (int)__popcll(mask & ((1ull << lane) - 1ull));
          idxbuf[e * CAP + pos] = tok;
        }
      }
    }
  }
}

__global__ void scan_kernel(const int* __restrict__ counts, int* __restrict__ bases) {
  if (threadIdx.x == 0) {
    int s = 0;
    for (int e = 0; e < NEXP; ++e) { bases[e] = s; s += counts[e]; }
  }
}

// GEMM1: h[slot][n] = relu(x[idx[slot]] @ W1[e] + b1[e]), bf16 out.
// Tile 128(M) x 128(N), BK=64, 4 waves each 64x64 (4x4 frags of 16x16x32).
__global__ __launch_bounds__(256) void gemm1_kernel(
    const bf16_t* __restrict__ xb, const bf16_t* __restrict__ w1t,
    const float* __restrict__ b1, const int* __restrict__ counts,
    const int* __restrict__ bases, const int* __restrict__ idxbuf,
    bf16_t* __restrict__ h) {
  const int e = blockIdx.z;
  const int cnt = counts[e];
  const int tm = blockIdx.x;
  if (tm * 128 >= cnt) return;
  const int nt = blockIdx.y;
  const int bse = bases[e];
  __shared__ __align__(16) bf16_t As[128 * 64];
  __shared__ __align__(16) bf16_t Bs[128 * 64];
  __shared__ int sidx[128];
  const int th = threadIdx.x;
  const int ln = th & 63, wv = th >> 6;
  if (th < 128) {
    int r = tm * 128 + th;
    sidx[th] = idxbuf[e * CAP + (r < cnt ? r : cnt - 1)];
  }
  __syncthreads();
  f32x4 acc[4][4] = {};
  const bf16_t* w1e = w1t + (size_t)e * 65536;
  const int wm = (wv & 1) * 64, wn = (wv >> 1) * 64;
  const int lr = ln & 15, lq = ln >> 4;
  for (int kk = 0; kk < 256; kk += 64) {
#pragma unroll
    for (int i = 0; i < 4; ++i) {
      int c = i * 256 + th;               // 16B chunk id, A: [128 r][8 j]
      int r = c >> 3, j = c & 7;
      async16(xb + (size_t)sidx[r] * 256 + kk + j * 8, &As[(i * 256 + wv * 64) * 8]);
    }
#pragma unroll
    for (int i = 0; i < 4; ++i) {
      int c = i * 256 + th;               // B: [128 n][8 j] from W1t[e][n][k]
      int n = c >> 3, j = c & 7;
      async16(w1e + (size_t)(nt * 128 + n) * 256 + kk + j * 8, &Bs[(i * 256 + wv * 64) * 8]);
    }
    __syncthreads();
#pragma unroll
    for (int kb = 0; kb < 2; ++kb) {
      bf16x8 af[4], bfr[4];
#pragma unroll
      for (int mi = 0; mi < 4; ++mi)
        af[mi] = *(const bf16x8*)&As[(wm + mi * 16 + lr) * 64 + kb * 32 + lq * 8];
#pragma unroll
      for (int ni = 0; ni < 4; ++ni)
        bfr[ni] = *(const bf16x8*)&Bs[(wn + ni * 16 + lr) * 64 + kb * 32 + lq * 8];
#pragma unroll
      for (int mi = 0; mi < 4; ++mi)
#pragma unroll
        for (int ni = 0; ni < 4; ++ni)
          acc[mi][ni] = __builtin_amdgcn_mfma_f32_16x16x32_bf16(af[mi], bfr[ni], acc[mi][ni], 0, 0, 0);
    }
    __syncthreads();
  }
#pragma unroll
  for (int ni = 0; ni < 4; ++ni) {
    int n = nt * 128 + wn + ni * 16 + lr;
    float bias = b1[e * 256 + n];
#pragma unroll
    for (int mi = 0; mi < 4; ++mi) {
#pragma unroll
      for (int r = 0; r < 4; ++r) {
        int rowb = wm + mi * 16 + lq * 4 + r;   // C layout: col=lane&15, row=quad*4+reg
        int row = tm * 128 + rowb;
        if (row < cnt) {
          float v = acc[mi][ni][r] + bias;
          v = v > 0.f ? v : 0.f;
          h[(size_t)(bse + row) * 256 + n] = (bf16_t)v;
        }
      }
    }
  }
}

// GEMM2: out[tok][n] = (h[slot] @ W2[e] + b2[e]) * gate, scattered fp32 store.
__global__ __launch_bounds__(256) void gemm2_kernel(
    const bf16_t* __restrict__ h, const bf16_t* __restrict__ w2t,
    const float* __restrict__ b2, const float* __restrict__ gateval,
    const int* __restrict__ counts, const int* __restrict__ bases,
    const int* __restrict__ idxbuf, float* __restrict__ out) {
  const int e = blockIdx.z;
  const int cnt = counts[e];
  const int tm = blockIdx.x;
  if (tm * 128 >= cnt) return;
  const int nt = blockIdx.y;
  const int bse = bases[e];
  __shared__ __align__(16) bf16_t As[128 * 64];
  __shared__ __align__(16) bf16_t Bs[128 * 64];
  __shared__ int sidx[128];
  __shared__ float sgv[128];
  const int th = threadIdx.x;
  const int ln = th & 63, wv = th >> 6;
  if (th < 128) {
    int r = tm * 128 + th;
    int t = idxbuf[e * CAP + (r < cnt ? r : cnt - 1)];
    sidx[th] = t;
    sgv[th] = gateval[t];
  }
  __syncthreads();
  f32x4 acc[4][4] = {};
  const bf16_t* w2e = w2t + (size_t)e * 65536;
  const int wm = (wv & 1) * 64, wn = (wv >> 1) * 64;
  const int lr = ln & 15, lq = ln >> 4;
  for (int kk = 0; kk < 256; kk += 64) {
#pragma unroll
    for (int i = 0; i < 4; ++i) {
      int c = i * 256 + th;
      int r = c >> 3, j = c & 7;
      int rg = tm * 128 + r; rg = rg < cnt ? rg : cnt - 1;
      async16(h + (size_t)(bse + rg) * 256 + kk + j * 8, &As[(i * 256 + wv * 64) * 8]);
    }
#pragma unroll
    for (int i = 0; i < 4; ++i) {
      int c = i * 256 + th;
      int n = c >> 3, j = c & 7;
      async16(w2e + (size_t)(nt * 128 + n) * 256 + kk + j * 8, &Bs[(i * 256 + wv * 64) * 8]);
    }
    __syncthreads();
#pragma unroll
    for (int kb = 0; kb < 2; ++kb) {
      bf16x8 af[4], bfr[4];
#pragma unroll
      for (int mi = 0; mi < 4; ++mi)
        af[mi] = *(const bf16x8*)&As[(wm + mi * 16 + lr) * 64 + kb * 32 + lq * 8];
#pragma unroll
      for (int ni = 0; ni < 4; ++ni)
        bfr[ni] = *(const bf16x8*)&Bs[(wn + ni * 16 + lr) * 64 + kb * 32 + lq * 8];
#pragma unroll
      for (int mi = 0; mi < 4; ++mi)
#pragma unroll
        for (int ni = 0; ni < 4; ++ni)
          acc[mi][ni] = __builtin_amdgcn_mfma_f32_16x16x32_bf16(af[mi], bfr[ni], acc[mi][ni], 0, 0, 0);
    }
    __syncthreads();
  }
#pragma unroll
  for (int ni = 0; ni < 4; ++ni) {
    int n = nt * 128 + wn + ni * 16 + lr;
    float bias = b2[e * 256 + n];
#pragma unroll
    for (int mi = 0; mi < 4; ++mi) {
#pragma unroll
      for (int r = 0; r < 4; ++r) {
        int rowb = wm + mi * 16 + lq * 4 + r;
        int row = tm * 128 + rowb;
        if (row < cnt) {
          int tok = sidx[rowb];
          out[(size_t)tok * 256 + n] = (acc[mi][ni][r] + bias) * sgv[rowb];
        }
      }
    }
  }
}

extern "C" void kernel_launch(void* const* d_in, const int* in_sizes, int n_in,
                              void* d_out, int out_size, void* d_ws, size_t ws_size,
                              hipStream_t stream) {
  (void)in_sizes; (void)n_in; (void)out_size; (void)ws_size;
  const float* x  = (const float*)d_in[0];
  const float* wg = (const float*)d_in[1];
  const float* W1 = (const float*)d_in[2];
  const float* b1 = (const float*)d_in[3];
  const float* W2 = (const float*)d_in[4];
  const float* b2 = (const float*)d_in[5];
  float* out = (float*)d_out;

  char* ws = (char*)d_ws;
  size_t off = 0;
  auto alloc = [&](size_t bytes) {
    void* p = ws + off;
    off += (bytes + 255) & ~(size_t)255;
    return p;
  };
  bf16_t* xb     = (bf16_t*)alloc((size_t)NTOK * DMODEL * 2);   // 32 MB
  bf16_t* hbuf   = (bf16_t*)alloc((size_t)NTOK * DMODEL * 2);   // 32 MB
  bf16_t* w1t    = (bf16_t*)alloc((size_t)NEXP * 256 * 256 * 2);
  bf16_t* w2t    = (bf16_t*)alloc((size_t)NEXP * 256 * 256 * 2);
  int*    idxbuf = (int*)alloc((size_t)NEXP * CAP * 4);         // 2 MB
  float*  gv     = (float*)alloc((size_t)NTOK * 4);
  float*  wgT    = (float*)alloc((size_t)NEXP * DMODEL * 4);
  int*    counts = (int*)alloc(64);
  int*    bases  = (int*)alloc(64);

  hipLaunchKernelGGL(prep_kernel, dim3(8), dim3(256), 0, stream, wg, wgT, counts);
  hipLaunchKernelGGL(castT_kernel, dim3(8, 8, 16), dim3(32, 8), 0, stream, W1, W2, w1t, w2t);
  hipLaunchKernelGGL(gate_kernel, dim3(NTOK / 64), dim3(512), 0, stream,
                     x, wgT, xb, gv, counts, idxbuf);
  hipLaunchKernelGGL(scan_kernel, dim3(1), dim3(64), 0, stream, counts, bases);
  hipLaunchKernelGGL(gemm1_kernel, dim3(512, 2, NEXP), dim3(256), 0, stream,
                     xb, w1t, b1, counts, bases, idxbuf, hbuf);
  hipLaunchKernelGGL(gemm2_kernel, dim3(512, 2, NEXP), dim3(256), 0, stream,
                     hbuf, w2t, b2, gv, counts, bases, idxbuf, out);
}